// Round 9
// baseline (190.716 us; speedup 1.0000x reference)
//
#include <hip/hip_runtime.h>

// CostVolume2D: B=8, H=256, W=512, C=32, n_disp=12, stride=1.
// cost[b,h,w,d] = sum_c |feat_l[b,h,w,c] - feat_r[b,h,w-d,c]|, feat_r zero-padded left.
//
// Block = 256 threads = one full row; thread t owns pixels (2t, 2t+1).
// P=2: the 13-column window col = 2t+E-11 (E=0..12) serves all 24 (pixel,d)
// pairs -> 52 ds_read_b128/pixel-pair-plane-pass vs 96/pixel in r7 (0.54x LDS).
//
// LDS layout per plane: 9 runs of 64 slots; within each 64-column run the glld
// SOURCE lane order is parity-permuted (lanes 0-31 -> even cols, 32-63 -> odd),
// so slot(col_rel) = 64*(n>>5) + (n&31) + 32*p with n = col_rel>>1, p = col_rel&1.
// The per-instruction address SET is still 64 consecutive columns x 16B (same
// coalescing as r7, which measured compulsory FETCH), unlike r3's 256B-stride
// sections that doubled FETCH. Reads at fixed (q,E): n = t + (E>>1) -> lanes
// form <=3 contiguous slot runs (conflict-free-ish); 7 shared base VGPRs, the
// rest folds into ds_read immediate offsets.
//
// 4 passes x 2 float4-planes, double-buffered: stage(pp+1) issued right after
// the barrier, in flight under compute(pp); drained by the next barrier.

constexpr int Wd    = 512;
constexpr int ND    = 12;
constexpr int NSLOT = 576;            // 16B slots per plane: 9 runs x 64
constexpr int NPASS = 4;              // 2 planes (8 channels) per pass

typedef float vfloat4 __attribute__((ext_vector_type(4)));

__device__ __forceinline__ float l1_4(float4 a, float4 b) {
    return fabsf(a.x - b.x) + fabsf(a.y - b.y) + fabsf(a.z - b.z) + fabsf(a.w - b.w);
}
__device__ __forceinline__ float abs4(float4 a) {
    return fabsf(a.x) + fabsf(a.y) + fabsf(a.z) + fabsf(a.w);
}

__global__ __launch_bounds__(256) void cost_volume_kernel(
    const float* __restrict__ fl,
    const float* __restrict__ fr,
    float* __restrict__ out)
{
    __shared__ float4 lds4[2][2 * NSLOT];          // 36864 B total

    const int t    = threadIdx.x;                  // pixel pair (2t, 2t+1)
    const int wave = t >> 6;
    const int lane = t & 63;
    const int bh   = blockIdx.x;                   // b*H + h
    const float* fr_row = fr + (size_t)bh * Wd * 32;
    const size_t pix0 = (size_t)bh * Wd + 2 * t;
    const float4* lp = reinterpret_cast<const float4*>(fl);

    // Read-address bases: n = t + m, m = E>>1 in [0,6].
    int basen[7];
    #pragma unroll
    for (int m = 0; m < 7; ++m) {
        const int n = t + m;
        basen[m] = ((n >> 5) << 6) + (n & 31);
    }

    // Stage planes {2pp, 2pp+1} into lds4[buf] (18 glld instrs split 5/5/4/4).
    auto stage = [&](int pp, int buf) {
        #pragma unroll
        for (int j = 0; j < 5; ++j) {
            const int i = wave + 4 * j;
            if (i < 18) {
                const int k = i >> 1, q = i & 1;
                int col = 64 * k + 2 * (lane & 31) + (lane >> 5) - 11;
                col = min(max(col, 0), Wd - 1);    // clamped slots never read validly
                __builtin_amdgcn_global_load_lds(
                    (const __attribute__((address_space(1))) void*)(fr_row + (size_t)col * 32 + (pp * 2 + q) * 4),
                    (__attribute__((address_space(3))) void*)(&lds4[buf][q * NSLOT + 64 * k + lane]),
                    16, 0, 0);
            }
        }
    };

    float res0[ND], res1[ND];
    #pragma unroll
    for (int d = 0; d < ND; ++d) { res0[d] = 0.f; res1[d] = 0.f; }
    float lsum0 = 0.f, lsum1 = 0.f;

    stage(0, 0);

    #pragma unroll
    for (int pp = 0; pp < NPASS; ++pp) {
        __syncthreads();                           // buf[pp&1] staged; prev reads done
        if (pp + 1 < NPASS) stage(pp + 1, (pp + 1) & 1);   // in flight under compute

        const int buf = pp & 1;
        #pragma unroll
        for (int q = 0; q < 2; ++q) {
            const float4 A0 = lp[pix0 * 8 + pp * 2 + q];
            const float4 A1 = lp[(pix0 + 1) * 8 + pp * 2 + q];
            lsum0 += abs4(A0);
            lsum1 += abs4(A1);
            const float4* plane = &lds4[buf][q * NSLOT];
            #pragma unroll
            for (int E = 0; E <= 12; ++E) {        // col = 2t + E - 11
                const float4 rv = plane[basen[E >> 1] + 32 * (E & 1)];
                if (E <= 11) res0[11 - E] += l1_4(A0, rv);   // d0 = 11-E
                if (E >= 1)  res1[12 - E] += l1_4(A1, rv);   // d1 = 12-E
            }
        }
    }

    // Left edge: w < d -> feat_r fully shifted out (zeros) -> sum|feat_l|.
    if (t < 6) {
        #pragma unroll
        for (int d = 0; d < ND; ++d) {
            if (d > 2 * t)     res0[d] = lsum0;
            if (d > 2 * t + 1) res1[d] = lsum1;
        }
    }

    // Nontemporal output stores: 24 contiguous floats per thread.
    vfloat4* op = reinterpret_cast<vfloat4*>(out + pix0 * ND);
    vfloat4 o0 = {res0[0], res0[1], res0[2],  res0[3]};
    vfloat4 o1 = {res0[4], res0[5], res0[6],  res0[7]};
    vfloat4 o2 = {res0[8], res0[9], res0[10], res0[11]};
    vfloat4 o3 = {res1[0], res1[1], res1[2],  res1[3]};
    vfloat4 o4 = {res1[4], res1[5], res1[6],  res1[7]};
    vfloat4 o5 = {res1[8], res1[9], res1[10], res1[11]};
    __builtin_nontemporal_store(o0, op + 0);
    __builtin_nontemporal_store(o1, op + 1);
    __builtin_nontemporal_store(o2, op + 2);
    __builtin_nontemporal_store(o3, op + 3);
    __builtin_nontemporal_store(o4, op + 4);
    __builtin_nontemporal_store(o5, op + 5);
}

extern "C" void kernel_launch(void* const* d_in, const int* in_sizes, int n_in,
                              void* d_out, int out_size, void* d_ws, size_t ws_size,
                              hipStream_t stream)
{
    const float* fl = (const float*)d_in[0];
    const float* fr = (const float*)d_in[1];
    float* out = (float*)d_out;

    const int grid = 8 * 256;                      // one block per (b, h) row
    cost_volume_kernel<<<grid, 256, 0, stream>>>(fl, fr, out);
}

// Round 10
// 119.189 us; speedup vs baseline: 1.6001x; 1.6001x over previous
//
#include <hip/hip_runtime.h>

// CostVolume2D: B=8, H=256, W=512, C=32, n_disp=12, stride=1.
// cost[b,h,w,d] = sum_c |feat_l[b,h,w,c] - feat_r[b,h,w-d,c]|, feat_r zero-padded left.
//
// Block = 256 threads = one full row; thread t owns pixels (2t, 2t+1)  [P=2:
// 13 window columns serve 24 (pixel,d) pairs -> 52 ds_read_b128/pixel vs 96 in r7].
// Two channel-half passes (16 ch = 4 float4-planes each) over ONE 33.8 KB buffer.
//
// Staging (r7-proven): direct global_load_lds, LDS dest linear in chunk index,
//   source = col*128B + q*16B (the exact r7 pattern that measured compulsory FETCH).
//   Plane ql chunk c holds col = c-11 (clamped); 33 instrs/pass over 4 waves.
// Reads (r4/r5/r7-proven pattern + P=2): plane ql at chunk 2t+E, E=0..12:
//   byte addr = ql*8448 + t*32 + E*16 -> ONE base VGPR (t*32), everything else
//   immediate. Lane stride = 2 chunks -> at most 2-way bank aliasing (~free, m136).
// Spill-proofing (r8/r9 lesson): outer pass loop unroll 1, no lambdas, no
//   register staging arrays.

constexpr int Wrow  = 512;
constexpr int ND    = 12;
constexpr int NSLOT = 528;            // 16B chunks per plane (523 used)
constexpr int NCHUNK = 4 * NSLOT;     // 2112 chunks = 33792 B

typedef float vfloat4 __attribute__((ext_vector_type(4)));

__device__ __forceinline__ float l1_4(float4 a, float4 b) {
    return fabsf(a.x - b.x) + fabsf(a.y - b.y) + fabsf(a.z - b.z) + fabsf(a.w - b.w);
}
__device__ __forceinline__ float abs4(float4 a) {
    return fabsf(a.x) + fabsf(a.y) + fabsf(a.z) + fabsf(a.w);
}

__global__ __launch_bounds__(256) void cost_volume_kernel(
    const float* __restrict__ fl,
    const float* __restrict__ fr,
    float* __restrict__ out)
{
    __shared__ float4 lds4[NCHUNK];

    const int t    = threadIdx.x;                 // pixel pair (2t, 2t+1)
    const int wave = t >> 6;
    const int lane = t & 63;
    const int bh   = blockIdx.x;                  // b*H + h
    const float* fr_row = fr + (size_t)bh * Wrow * 32;
    const size_t pix0 = (size_t)bh * Wrow + 2 * t;
    const float4* lp = reinterpret_cast<const float4*>(fl);

    float res0[ND], res1[ND];
    #pragma unroll
    for (int d = 0; d < ND; ++d) { res0[d] = 0.f; res1[d] = 0.f; }
    float lsum0 = 0.f, lsum1 = 0.f;

    #pragma unroll 1
    for (int h = 0; h < 2; ++h) {
        if (h) __syncthreads();                   // pass-0 reads done before overwrite

        // ---- stage 4 planes of channel-half h (33 glld instrs, wave w takes i=w+4j)
        #pragma unroll
        for (int j = 0; j < 9; ++j) {
            const int i = wave + 4 * j;
            if (i < 33) {
                const int g  = i * 64 + lane;     // chunk 0..2111
                const int ql = g / NSLOT;
                const int c  = g - ql * NSLOT;
                int col = c - 11;
                col = min(max(col, 0), Wrow - 1); // guard cols clamped, never used
                __builtin_amdgcn_global_load_lds(
                    (const __attribute__((address_space(1))) void*)(fr_row + (size_t)col * 32 + (h * 4 + ql) * 4),
                    (__attribute__((address_space(3))) void*)(lds4 + g),
                    16, 0, 0);
            }
        }

        // ---- feat_l quarters for both pixels (issued under glld latency)
        float4 L0[4], L1[4];
        #pragma unroll
        for (int ql = 0; ql < 4; ++ql) {
            L0[ql] = lp[pix0 * 8 + h * 4 + ql];
            L1[ql] = lp[(pix0 + 1) * 8 + h * 4 + ql];
            lsum0 += abs4(L0[ql]);
            lsum1 += abs4(L1[ql]);
        }

        __syncthreads();                          // drains glld + visibility

        // ---- 13 window cols serve 24 (pixel,d) pairs; one base + imm offsets
        #pragma unroll
        for (int ql = 0; ql < 4; ++ql) {
            const float4* base = &lds4[ql * NSLOT + 2 * t];  // chunk 2t+E
            #pragma unroll
            for (int E = 0; E <= 12; ++E) {       // col = 2t + E - 11
                const float4 rv = base[E];
                if (E <= 11) res0[11 - E] += l1_4(L0[ql], rv);   // d0 = 11-E
                if (E >= 1)  res1[12 - E] += l1_4(L1[ql], rv);   // d1 = 12-E
            }
        }
    }

    // ---- left edge: w < d -> feat_r fully shifted out (zeros) -> sum|feat_l|
    if (t < 6) {
        #pragma unroll
        for (int d = 0; d < ND; ++d) {
            if (d > 2 * t)     res0[d] = lsum0;
            if (d > 2 * t + 1) res1[d] = lsum1;
        }
    }

    // ---- nontemporal stores: 24 contiguous floats/thread, 96B-coalesced
    vfloat4* op = reinterpret_cast<vfloat4*>(out + pix0 * ND);
    vfloat4 o0 = {res0[0], res0[1], res0[2],  res0[3]};
    vfloat4 o1 = {res0[4], res0[5], res0[6],  res0[7]};
    vfloat4 o2 = {res0[8], res0[9], res0[10], res0[11]};
    vfloat4 o3 = {res1[0], res1[1], res1[2],  res1[3]};
    vfloat4 o4 = {res1[4], res1[5], res1[6],  res1[7]};
    vfloat4 o5 = {res1[8], res1[9], res1[10], res1[11]};
    __builtin_nontemporal_store(o0, op + 0);
    __builtin_nontemporal_store(o1, op + 1);
    __builtin_nontemporal_store(o2, op + 2);
    __builtin_nontemporal_store(o3, op + 3);
    __builtin_nontemporal_store(o4, op + 4);
    __builtin_nontemporal_store(o5, op + 5);
}

extern "C" void kernel_launch(void* const* d_in, const int* in_sizes, int n_in,
                              void* d_out, int out_size, void* d_ws, size_t ws_size,
                              hipStream_t stream)
{
    const float* fl = (const float*)d_in[0];
    const float* fr = (const float*)d_in[1];
    float* out = (float*)d_out;

    const int grid = 8 * 256;                     // one block per (b, h) row
    cost_volume_kernel<<<grid, 256, 0, stream>>>(fl, fr, out);
}

// Round 11
// 115.012 us; speedup vs baseline: 1.6582x; 1.0363x over previous
//
#include <hip/hip_runtime.h>

// CostVolume2D: B=8, H=256, W=512, C=32, n_disp=12, stride=1.
// cost[b,h,w,d] = sum_c |feat_l[b,h,w,c] - feat_r[b,h,w-d,c]|, feat_r zero-padded left.
//
// Block = 256 threads = ONE FULL ROW; thread t owns pixels (2t, 2t+1).
// Single stage of all 32 channels (r10's 2-pass split refetched every line:
// FETCH 292MB): plane-major lds4[ql][col], ql = float4-quarter, col = 0..511,
// 4096 chunks = 64KB exactly. No halo: negative cols are the zero-pad branch,
// fixed up via lsum; their reads (t<6, LDS OOB-low / prev-plane tail) land in
// accumulators that the fixup overwrites.
//
// Stage: 64 runs of 64 lanes; run r -> plane r>>3, chunk ((r&7)<<6)+lane
// (no div). Dest lane-linear (legal glld), src = col*128B + ql*16B — the
// r7-verified pattern (compulsory FETCH, sectors merged in flight).
// Reads: ONE base VGPR (byte (2t-11)*16); all 104 ds_read_b128 use imm
// offsets ql*8192 + E*16 (max 57536 < 64K). Lane stride 32B = 4-way bank
// conflict (~+4cyc/instr, measured r10) — accepted, hides under HBM.

constexpr int ND = 12;

typedef float vfloat4 __attribute__((ext_vector_type(4)));

__device__ __forceinline__ float l1_4(float4 a, float4 b) {
    return fabsf(a.x - b.x) + fabsf(a.y - b.y) + fabsf(a.z - b.z) + fabsf(a.w - b.w);
}
__device__ __forceinline__ float abs4(float4 a) {
    return fabsf(a.x) + fabsf(a.y) + fabsf(a.z) + fabsf(a.w);
}

__global__ __launch_bounds__(256) void cost_volume_kernel(
    const float* __restrict__ fl,
    const float* __restrict__ fr,
    float* __restrict__ out)
{
    __shared__ float4 lds4[8 * 512];               // 65536 B exactly

    const int t    = threadIdx.x;                  // pixel pair (2t, 2t+1)
    const int wave = t >> 6;
    const int lane = t & 63;
    const int bh   = blockIdx.x;                   // b*H + h
    const float* fr_row = fr + (size_t)bh * 512 * 32;
    const size_t pix0 = (size_t)bh * 512 + 2 * t;
    const float4* lp = reinterpret_cast<const float4*>(fl);

    // ---- stage all 8 planes: 64 runs, wave w takes r = w + 4j (16 glld/thread)
    #pragma unroll
    for (int j = 0; j < 16; ++j) {
        const int r  = wave + 4 * j;
        const int ql = r >> 3;
        const int c  = ((r & 7) << 6) + lane;      // col 0..511
        __builtin_amdgcn_global_load_lds(
            (const __attribute__((address_space(1))) void*)(fr_row + (size_t)c * 32 + ql * 4),
            (__attribute__((address_space(3))) void*)(lds4 + (ql << 9) + c),
            16, 0, 0);
    }

    // ---- feat_l for both pixels (in flight under glld latency)
    float4 L0[8], L1[8];
    float lsum0 = 0.f, lsum1 = 0.f;
    #pragma unroll
    for (int ql = 0; ql < 8; ++ql) {
        L0[ql] = lp[pix0 * 8 + ql];
        L1[ql] = lp[(pix0 + 1) * 8 + ql];
        lsum0 += abs4(L0[ql]);
        lsum1 += abs4(L1[ql]);
    }

    float res0[ND], res1[ND];
    #pragma unroll
    for (int d = 0; d < ND; ++d) { res0[d] = 0.f; res1[d] = 0.f; }

    __syncthreads();                               // drains glld + visibility

    // ---- 13 window cols serve 24 (pixel,d) pairs per plane; 1 base + imm offs
    const char* lbase = (const char*)lds4 + (2 * t - 11) * 16;
    #pragma unroll
    for (int ql = 0; ql < 8; ++ql) {
        const float4 A0 = L0[ql], A1 = L1[ql];
        #pragma unroll
        for (int E = 0; E <= 12; ++E) {            // col = 2t + E - 11
            const float4 rv = *reinterpret_cast<const float4*>(lbase + (ql * 8192 + E * 16));
            if (E <= 11) res0[11 - E] += l1_4(A0, rv);   // d0 = 11-E
            if (E >= 1)  res1[12 - E] += l1_4(A1, rv);   // d1 = 12-E
        }
    }

    // ---- left edge: w < d -> feat_r fully shifted out (zeros) -> sum|feat_l|
    if (t < 6) {
        #pragma unroll
        for (int d = 0; d < ND; ++d) {
            if (d > 2 * t)     res0[d] = lsum0;
            if (d > 2 * t + 1) res1[d] = lsum1;
        }
    }

    // ---- nontemporal stores: 24 contiguous floats/thread
    vfloat4* op = reinterpret_cast<vfloat4*>(out + pix0 * ND);
    vfloat4 o0 = {res0[0], res0[1], res0[2],  res0[3]};
    vfloat4 o1 = {res0[4], res0[5], res0[6],  res0[7]};
    vfloat4 o2 = {res0[8], res0[9], res0[10], res0[11]};
    vfloat4 o3 = {res1[0], res1[1], res1[2],  res1[3]};
    vfloat4 o4 = {res1[4], res1[5], res1[6],  res1[7]};
    vfloat4 o5 = {res1[8], res1[9], res1[10], res1[11]};
    __builtin_nontemporal_store(o0, op + 0);
    __builtin_nontemporal_store(o1, op + 1);
    __builtin_nontemporal_store(o2, op + 2);
    __builtin_nontemporal_store(o3, op + 3);
    __builtin_nontemporal_store(o4, op + 4);
    __builtin_nontemporal_store(o5, op + 5);
}

extern "C" void kernel_launch(void* const* d_in, const int* in_sizes, int n_in,
                              void* d_out, int out_size, void* d_ws, size_t ws_size,
                              hipStream_t stream)
{
    const float* fl = (const float*)d_in[0];
    const float* fr = (const float*)d_in[1];
    float* out = (float*)d_out;

    const int grid = 8 * 256;                      // one block per (b, h) row
    cost_volume_kernel<<<grid, 256, 0, stream>>>(fl, fr, out);
}

// Round 12
// 88.784 us; speedup vs baseline: 2.1481x; 1.2954x over previous
//
#include <hip/hip_runtime.h>

// CostVolume2D: B=8, H=256, W=512, C=32, n_disp=12, stride=1.
// cost[b,h,w,d] = sum_c |feat_l[b,h,w,c] - feat_r[b,h,w-d,c]|, feat_r zero-padded left.
//
// Block = 256 threads = half a row, 1 pixel/thread, TWO channel passes (16 ch),
// ONE 17.4 KB buffer  [r8 shape: measured compulsory FETCH 140 MB — the
// half-row per-pass footprint fits the per-CU L2 share, unlike full-row r10/r11].
// Staging (r7-proven): direct global_load_lds, dest lane-linear, src
//   col*128B + q*16B; wave w stages plane w of the half. Compulsory FETCH.
// Reads (r7-proven): plane-major NCOL=272, lane-consecutive, one base + 12 imm
//   offsets -> 0 bank conflicts.
// r12 fix vs r8: #pragma unroll 1 on the pass loop (r10: holds VGPR down) +
//   __launch_bounds__(256,6) -> VGPR cap 85 -> 6 blocks/CU (24 waves) vs r7's
//   4 blocks: inter-block phase overlap (r7 = HBM + LDS summed, not max).

constexpr int Wd   = 512;
constexpr int ND   = 12;
constexpr int NCOL = 272;             // per-plane chunk capacity (267 used)

typedef float vfloat4 __attribute__((ext_vector_type(4)));

__device__ __forceinline__ float l1_4(float4 a, float4 b) {
    return fabsf(a.x - b.x) + fabsf(a.y - b.y) + fabsf(a.z - b.z) + fabsf(a.w - b.w);
}
__device__ __forceinline__ float abs4(float4 a) {
    return fabsf(a.x) + fabsf(a.y) + fabsf(a.z) + fabsf(a.w);
}

__global__ __launch_bounds__(256, 6) void cost_volume_kernel(
    const float* __restrict__ fl,
    const float* __restrict__ fr,
    float* __restrict__ out)
{
    __shared__ float4 lds4[4 * NCOL];              // 17408 B

    const int t    = threadIdx.x;
    const int wave = t >> 6;
    const int lane = t & 63;
    const int wstart = (blockIdx.x & 1) * 256;
    const int bh     = blockIdx.x >> 1;            // b*H + h
    const float* fr_row = fr + (size_t)bh * Wd * 32;

    const int w = wstart + t;
    const size_t pix = (size_t)bh * Wd + w;
    const float4* lp = reinterpret_cast<const float4*>(fl) + pix * 8;

    float res[ND];
    #pragma unroll
    for (int d = 0; d < ND; ++d) res[d] = 0.f;
    float lsum = 0.f;

    #pragma unroll 1
    for (int h = 0; h < 2; ++h) {
        if (h) __syncthreads();                    // pass-0 reads done before overwrite

        // ---- stage channel-half h: wave w stages plane w (global quarter h*4+w)
        #pragma unroll
        for (int run = 0; run < 5; ++run) {
            const int colr = run * 64 + lane;
            int col = wstart - 11 + colr;
            col = max(col, 0);                     // guard cols clamped, never used
            if (run < 4 || lane < 267 - 256) {
                __builtin_amdgcn_global_load_lds(
                    (const __attribute__((address_space(1))) void*)(fr_row + (size_t)col * 32 + (h * 4 + wave) * 4),
                    (__attribute__((address_space(3))) void*)(lds4 + wave * NCOL + colr),
                    16, 0, 0);
            }
        }

        // ---- feat_l channel-half h (issued under glld latency)
        float4 L[4];
        #pragma unroll
        for (int ql = 0; ql < 4; ++ql) {
            L[ql] = lp[h * 4 + ql];
            lsum += abs4(L[ql]);
        }

        __syncthreads();                           // drains glld + visibility

        // ---- 12 disparities: per plane one base + 12 imm offsets, 0 conflicts
        #pragma unroll
        for (int ql = 0; ql < 4; ++ql) {
            const float4 Lq = L[ql];
            const float4* base = &lds4[ql * NCOL + t];   // colr = t + (11-d)
            #pragma unroll
            for (int d = 0; d < ND; ++d) {
                res[d] += l1_4(Lq, base[11 - d]);
            }
        }
    }

    // ---- left edge: w < d -> feat_r fully shifted out (zeros) -> sum|feat_l|
    #pragma unroll
    for (int d = 0; d < ND; ++d)
        if (w < d) res[d] = lsum;

    // ---- nontemporal output stores (don't evict inputs from L3)
    vfloat4* op = reinterpret_cast<vfloat4*>(out + pix * ND);
    vfloat4 o0 = {res[0], res[1], res[2],  res[3]};
    vfloat4 o1 = {res[4], res[5], res[6],  res[7]};
    vfloat4 o2 = {res[8], res[9], res[10], res[11]};
    __builtin_nontemporal_store(o0, op + 0);
    __builtin_nontemporal_store(o1, op + 1);
    __builtin_nontemporal_store(o2, op + 2);
}

extern "C" void kernel_launch(void* const* d_in, const int* in_sizes, int n_in,
                              void* d_out, int out_size, void* d_ws, size_t ws_size,
                              hipStream_t stream)
{
    const float* fl = (const float*)d_in[0];
    const float* fr = (const float*)d_in[1];
    float* out = (float*)d_out;

    const int grid = 8 * 256 * 2;                  // (b,h) x 2 half-rows
    cost_volume_kernel<<<grid, 256, 0, stream>>>(fl, fr, out);
}

// Round 13
// 64.919 us; speedup vs baseline: 2.9377x; 1.3676x over previous
//
#include <hip/hip_runtime.h>

// CostVolume2D: B=8, H=256, W=512, C=32, n_disp=12, stride=1.
// cost[b,h,w,d] = sum_c |feat_l[b,h,w,c] - feat_r[b,h,w-d,c]|, feat_r zero-padded left.
//
// BARRIER-FREE wave-autonomous design (r13). r7 = 57.8us ~= HBM(29us) + LDS(31us)
// summed: __syncthreads kept all waves phase-locked and drained vmcnt(0) block-wide.
// Here each wave owns a private 64-pixel segment (+11-col halo) in its OWN LDS
// region -> no cross-wave deps -> no barriers; per-wave s_waitcnt vmcnt(0) only.
// 16 resident waves/CU in naturally staggered phases overlap HBM and LDS pipes.
//
// Per-wave LDS: plane-major lds[q][colr], q=float4-quarter 0..7, colr=0..75
// (col = seg-11+colr, clamped; colr 75 = pad). 608 chunks = 9728 B; block of
// 4 waves = 38912 B -> 4 blocks/CU (LDS-bound), 16 waves/CU.
// Stage (r7-proven source pattern, compulsory FETCH): 10 glld/wave, dest
//   linear (uniform base + lane*16), source col*128B + q*16B; one wave's 10
//   instrs consume its whole 9.7KB window -> sectors merged, no refetch.
// Reads (r7-proven, 0 conflicts): lane-consecutive b128; 12 addr VGPRs
//   (one per d), all 96 reads use imm offsets q*1216.

constexpr int ND     = 12;
constexpr int NCOL   = 76;              // 64 + 11 halo + 1 pad
constexpr int WCHUNK = 8 * NCOL;        // 608 chunks per wave

typedef float vfloat4 __attribute__((ext_vector_type(4)));

__device__ __forceinline__ float l1_4(float4 a, float4 b) {
    return fabsf(a.x - b.x) + fabsf(a.y - b.y) + fabsf(a.z - b.z) + fabsf(a.w - b.w);
}
__device__ __forceinline__ float abs4(float4 a) {
    return fabsf(a.x) + fabsf(a.y) + fabsf(a.z) + fabsf(a.w);
}

__global__ __launch_bounds__(256) void cost_volume_kernel(
    const float* __restrict__ fl,
    const float* __restrict__ fr,
    float* __restrict__ out)
{
    __shared__ float4 lds4[4 * WCHUNK];            // 38912 B

    const int t    = threadIdx.x;
    const int wave = t >> 6;
    const int lane = t & 63;
    const int bh   = blockIdx.x >> 1;              // b*H + h
    const int seg  = (blockIdx.x & 1) * 256 + wave * 64;   // this wave's pixel base
    const float* fr_row = fr + (size_t)bh * 512 * 32;
    float4* wb = lds4 + wave * WCHUNK;             // this wave's private region

    // ---- stage: 10 glld, dest linear in g, content plane-major (g = q*76+colr)
    #pragma unroll
    for (int it = 0; it < 10; ++it) {
        const int g = it * 64 + lane;
        if (it < 9 || lane < WCHUNK - 576) {       // last instr: 32 active lanes
            const int q    = g / NCOL;
            const int colr = g - q * NCOL;
            int col = seg - 11 + colr;
            col = min(max(col, 0), 511);           // halo clamp; junk never read validly
            __builtin_amdgcn_global_load_lds(
                (const __attribute__((address_space(1))) void*)(fr_row + (size_t)col * 32 + q * 4),
                (__attribute__((address_space(3))) void*)(wb + g),
                16, 0, 0);
        }
    }

    // ---- feat_l (issued under glld latency)
    const int w = seg + lane;
    const size_t pix = (size_t)bh * 512 + w;
    const float4* lp = reinterpret_cast<const float4*>(fl) + pix * 8;
    float4 L[8];
    float lsum = 0.f;
    #pragma unroll
    for (int q = 0; q < 8; ++q) { L[q] = lp[q]; lsum += abs4(L[q]); }

    // ---- wait for THIS wave's loads only (no block-wide barrier drain)
    asm volatile("s_waitcnt vmcnt(0)" ::: "memory");
    __builtin_amdgcn_sched_barrier(0);

    // ---- 96 ds_read_b128: 12 base addrs (per d), imm offsets q*1216; r7 loop shape
    float res[ND];
    #pragma unroll
    for (int d = 0; d < ND; ++d) res[d] = 0.f;

    #pragma unroll
    for (int q = 0; q < 8; ++q) {
        const float4 Lq = L[q];
        const float4* base = wb + q * NCOL + lane + 11;   // colr = lane + 11 - d
        #pragma unroll
        for (int d = 0; d < ND; ++d) {
            res[d] += l1_4(Lq, base[-d]);
        }
    }

    // ---- left edge: w < d -> feat_r fully shifted out (zeros) -> sum|feat_l|
    #pragma unroll
    for (int d = 0; d < ND; ++d)
        if (w < d) res[d] = lsum;

    // ---- nontemporal stores: 48B contiguous per thread
    vfloat4* op = reinterpret_cast<vfloat4*>(out + pix * ND);
    vfloat4 o0 = {res[0], res[1], res[2],  res[3]};
    vfloat4 o1 = {res[4], res[5], res[6],  res[7]};
    vfloat4 o2 = {res[8], res[9], res[10], res[11]};
    __builtin_nontemporal_store(o0, op + 0);
    __builtin_nontemporal_store(o1, op + 1);
    __builtin_nontemporal_store(o2, op + 2);
}

extern "C" void kernel_launch(void* const* d_in, const int* in_sizes, int n_in,
                              void* d_out, int out_size, void* d_ws, size_t ws_size,
                              hipStream_t stream)
{
    const float* fl = (const float*)d_in[0];
    const float* fr = (const float*)d_in[1];
    float* out = (float*)d_out;

    const int grid = 8 * 256 * 2;                  // (b,h) x 2 half-rows
    cost_volume_kernel<<<grid, 256, 0, stream>>>(fl, fr, out);
}